// Round 4
// baseline (442.179 us; speedup 1.0000x reference)
//
#include <hip/hip_runtime.h>
#include <hip/hip_bf16.h>

// GraphNetwork GAT: B=4, N=2048, I=32, H=64, O=32, E=2, HD=2, D1=256
// R10: TLP over ILP. mac: block=(i-tile, etype-pair), 8 waves = 2 heads x
// 4 k-quarters, grid 1024 (4 blocks/CU, 32 waves/CU), simple single-buffered
// body under (512,8); k-quarters combined in LDS (no cross-block partials).
// stats: 2 j per thread, float4 edge loads, 8 accum chains. out: 1024 thr.

constexpr int B_  = 4;
constexpr int N_  = 2048;
constexpr int I_  = 32;
constexpr int H_  = 64;
constexpr int O_  = 32;
constexpr int EH_ = 4;          // E*HD combos, c = e*2 + h
constexpr int D1_ = 256;        // H*HD*E
constexpr int BN_ = B_ * N_;    // 8192
constexpr int NC_ = 64;         // i-chunks for softmax stats
constexpr int CH_ = N_ / NC_;   // 32
constexpr int TI_ = 16;         // msg rows per block (one MFMA m-tile)
constexpr int TK_ = 32;         // k-tile (one MFMA K)
constexpr int NKT_ = N_ / TK_;  // 64 k-tiles

typedef __bf16 bf16x8 __attribute__((ext_vector_type(8)));
typedef float floatx4 __attribute__((ext_vector_type(4)));

constexpr float L2E_ = 1.4426950408889634f;   // log2(e)

__device__ __forceinline__ unsigned short f2b(float f) {
    unsigned int u = __float_as_uint(f);
    return (unsigned short)((u + 0x7fffu + ((u >> 16) & 1u)) >> 16);
}

__device__ __forceinline__ float fexp2(float x) {
#if __has_builtin(__builtin_amdgcn_exp2f)
    return __builtin_amdgcn_exp2f(x);      // v_exp_f32 (exp2) direct
#else
    return __expf(x * 0.6931471805599453f);
#endif
}

// ------------------------------------------------- fused preprocessing
// blocks [0,2048): embed; [2048,2112): pack Wf0 (din=64); [2112,2368): Wf1
__global__ __launch_bounds__(256) void prep_kernel(
        const float* __restrict__ nodes, const float* __restrict__ W_emb,
        const float* __restrict__ b_emb, const float* __restrict__ Wf0,
        const float* __restrict__ Wf1, unsigned short* __restrict__ state0B,
        unsigned short* __restrict__ WfB0, unsigned short* __restrict__ WfB1) {
    int blk = blockIdx.x;
    int t = threadIdx.x;
    __shared__ float sn[4][I_];
    if (blk < 2048) {
        int r = t >> 6, h = t & 63;
        if (t < 4 * I_) {
            int rr = t / I_, ii = t % I_;
            sn[rr][ii] = nodes[(size_t)(blk * 4 + rr) * I_ + ii];
        }
        __syncthreads();
        float acc = b_emb[h];
        #pragma unroll
        for (int i = 0; i < I_; ++i) acc += sn[r][i] * W_emb[i * H_ + h];
        state0B[(size_t)(blk * 4 + r) * H_ + h] = f2b(acc);
    } else if (blk < 2048 + 64) {
        int o = (blk - 2048) * 256 + t;         // din=64
        int k = o & 63, n = (o >> 6) & 63, c = o >> 12;
        WfB0[o] = f2b(Wf0[((size_t)c * 64 + k) * 64 + n]);
    } else {
        int o = (blk - 2112) * 256 + t;         // din=256
        int k = o & 255, n = (o >> 8) & 63, c = o >> 14;
        WfB1[o] = f2b(Wf1[((size_t)c * 256 + k) * 64 + n]);
    }
}

// ---------------------------------------------------- Wh + a1/a2 via MFMA
// a1/a2 outputs are PRE-SCALED by log2(e) for the log2-domain softmax.
template <int DIN>
__global__ __launch_bounds__(256) void wh_a_mfma_kernel(
        const unsigned short* __restrict__ stateB, const unsigned short* __restrict__ WfB,
        const float* __restrict__ w1, const float* __restrict__ b1,
        const float* __restrict__ w2, const float* __restrict__ b2,
        unsigned short* __restrict__ WhB, float* __restrict__ a1,
        float* __restrict__ a2) {
    int t = threadIdx.x;
    int lane = t & 63, wv = t >> 6;             // wv = c
    int col = lane & 15, qd = lane >> 4;
    int bn0 = blockIdx.x * TI_;                 // grid BN/16 = 512
    int b = bn0 >> 11;

    floatx4 acc[4] = {{0,0,0,0},{0,0,0,0},{0,0,0,0},{0,0,0,0}};
    const unsigned short* __restrict__ ap = stateB + (size_t)(bn0 + col) * DIN + qd * 8;
    const unsigned short* __restrict__ bp = WfB + ((size_t)(wv * 64 + col) * DIN + qd * 8);
    #pragma unroll
    for (int k0 = 0; k0 < DIN; k0 += 32) {
        bf16x8 af = *(const bf16x8*)(ap + k0);
        #pragma unroll
        for (int nt = 0; nt < 4; ++nt) {
            bf16x8 bf = *(const bf16x8*)(bp + (size_t)nt * 16 * DIN + k0);
            acc[nt] = __builtin_amdgcn_mfma_f32_16x16x32_bf16(af, bf, acc[nt], 0, 0, 0);
        }
    }
    // acc[nt][r] = Wh[bn0 + qd*4 + r][nt*16 + col]
    int nb = ((bn0 & 2047) >> 3) + (qd >> 1);
    #pragma unroll
    for (int nt = 0; nt < 4; ++nt) {
        unsigned int lo = (unsigned int)f2b(acc[nt][0]) | ((unsigned int)f2b(acc[nt][1]) << 16);
        unsigned int hi = (unsigned int)f2b(acc[nt][2]) | ((unsigned int)f2b(acc[nt][3]) << 16);
        uint2 v = make_uint2(lo, hi);
        *(uint2*)(WhB + ((((size_t)(wv * B_ + b) * 256 + nb) * 64 + nt * 16 + col) * 8
                         + (qd & 1) * 4)) = v;
    }
    // a1/a2 row dots, butterfly over col lanes
    float p1[4] = {}, p2[4] = {};
    #pragma unroll
    for (int nt = 0; nt < 4; ++nt) {
        float w1n = w1[wv * H_ + nt * 16 + col];
        float w2n = w2[wv * H_ + nt * 16 + col];
        #pragma unroll
        for (int r = 0; r < 4; ++r) {
            p1[r] += acc[nt][r] * w1n;
            p2[r] += acc[nt][r] * w2n;
        }
    }
    #pragma unroll
    for (int m = 1; m < 16; m <<= 1)
        #pragma unroll
        for (int r = 0; r < 4; ++r) {
            p1[r] += __shfl_xor(p1[r], m, 64);
            p2[r] += __shfl_xor(p2[r], m, 64);
        }
    if (col == 0) {
        float b1c = b1[wv], b2c = b2[wv];
        #pragma unroll
        for (int r = 0; r < 4; ++r) {
            a1[(size_t)wv * BN_ + bn0 + qd * 4 + r] = (p1[r] + b1c) * L2E_;
            a2[(size_t)wv * BN_ + bn0 + qd * 4 + r] = (p2[r] + b2c) * L2E_;
        }
    }
}

// -------------------------------------------------- column softmax stats
// Direct sum-of-exp2 (range-safe). 2 j per thread, float4 edge loads,
// 8 independent accumulation chains. Grid B*NC*(N/512) = 1024.
__global__ __launch_bounds__(256) void stats_kernel(
        const float* __restrict__ edges, const float* __restrict__ a1,
        const float* __restrict__ a2, float* __restrict__ ps) {
    int blk = blockIdx.x;
    int jt = blk & 3;                           // 4 j-tiles of 512
    int ic = (blk >> 2) & (NC_ - 1);
    int b  = blk >> 8;
    int t = threadIdx.x;
    int j0 = jt * 512 + t * 2;
    __shared__ float sa1[EH_][CH_];
    if (t < EH_ * CH_) {
        int cc = t >> 5, ii = t & 31;
        sa1[cc][ii] = a1[(size_t)cc * BN_ + b * N_ + ic * CH_ + ii];
    }
    __syncthreads();
    float a2x[EH_], a2y[EH_], s0[EH_], s1[EH_];
    #pragma unroll
    for (int cc = 0; cc < EH_; ++cc) {
        float2 av = *(const float2*)(a2 + (size_t)cc * BN_ + b * N_ + j0);
        a2x[cc] = av.x; a2y[cc] = av.y;
        s0[cc] = 0.f; s1[cc] = 0.f;
    }
    const float4* __restrict__ ep =
        (const float4*)edges + (((size_t)(b * N_ + ic * CH_) * N_ + j0) >> 1);
    #pragma unroll 4
    for (int ii = 0; ii < CH_; ++ii) {
        float4 u = ep[(size_t)ii * (N_ >> 1)];  // [e0 j0, e1 j0, e0 j1, e1 j1]
        #pragma unroll
        for (int cc = 0; cc < EH_; ++cc) {
            float base = sa1[cc][ii];
            float xa = base + a2x[cc];
            float xb = base + a2y[cc];
            float la = fmaxf(xa, 0.2f * xa);
            float lb = fmaxf(xb, 0.2f * xb);
            float ea = (cc < 2) ? u.x : u.y;
            float eb = (cc < 2) ? u.z : u.w;
            s0[cc] += fexp2(fmaf(ea, L2E_, la));
            s1[cc] += fexp2(fmaf(eb, L2E_, lb));
        }
    }
    #pragma unroll
    for (int cc = 0; cc < EH_; ++cc)
        *(float2*)&ps[((size_t)ic * EH_ + cc) * BN_ + b * N_ + j0] =
            make_float2(s0[cc], s1[cc]);
}

// ---------------------------------- fused combine + WhB denominator fold
// Each block: one (c,b), 4 nb chunks (32 k). t<32 computes S_k = sum_ic ps,
// D_k = 1/S_k; then all 256 threads scale one 8-ushort WhB chunk in place.
__global__ __launch_bounds__(256) void scale_kernel(
        const float* __restrict__ ps, unsigned short* __restrict__ WhB) {
    int t = threadIdx.x;
    int m0 = blockIdx.x * 256;              // chunk base, grid 1024
    int cb = m0 >> 14;
    int c = cb >> 2, b = cb & 3;
    int k0 = ((m0 >> 6) & 255) * 8;         // 32 consecutive k
    __shared__ float sD[32];
    if (t < 32) {
        float S = 0.f;
        const float* pp = ps + (size_t)c * BN_ + b * N_ + k0 + t;
        #pragma unroll 8
        for (int ic = 0; ic < NC_; ++ic) S += pp[(size_t)ic * EH_ * BN_];
        sD[t] = 1.f / S;
    }
    __syncthreads();
    unsigned short* wp = WhB + (size_t)(m0 + t) * 8;
    uint4 w = *(const uint4*)wp;
    int nbo = (t >> 6) * 8;
    unsigned int words[4] = {w.x, w.y, w.z, w.w};
    #pragma unroll
    for (int q = 0; q < 4; ++q) {
        float lo = __uint_as_float((words[q] & 0xffffu) << 16) * sD[nbo + 2 * q];
        float hi = __uint_as_float(words[q] & 0xffff0000u) * sD[nbo + 2 * q + 1];
        words[q] = (unsigned)f2b(lo) | ((unsigned)f2b(hi) << 16);
    }
    *(uint4*)wp = make_uint4(words[0], words[1], words[2], words[3]);
}

// ------------------------------------------------------------- MFMA MAC
// Grid 1024: blk = g*2 + cp (cp = etype). Block: 16 i-rows, both heads of
// etype cp, full k. 8 waves = (kq 0..3) x (cl head 0..1); each wave 16
// k-tiles. A-fragment att built in registers; a2 staged in LDS (2 heads);
// denominator pre-folded into WhB. k-quarters combined via LDS tree.
// LAST=0: out = state1B columns [cp*128, cp*128+128); LAST=1: po partials
template <int LAST>
__global__ __launch_bounds__(512, 8) void mac_kernel(
        const float* __restrict__ edges, const float* __restrict__ a1,
        const float* __restrict__ a2s, const unsigned short* __restrict__ WhB,
        const float* __restrict__ bias, void* __restrict__ outv) {
    int t = threadIdx.x;                    // 512
    int blk = blockIdx.x;                   // 1024
    int cp = blk & 1;                       // etype
    int g  = blk >> 1;                      // 512 = b*128 + it
    int b  = g >> 7;
    int i0 = (g & 127) * TI_;
    int lane = t & 63, wv = t >> 6;
    int kq = wv >> 1;                       // k-quarter 0..3
    int cl = wv & 1;                        // head
    int c  = cp * 2 + cl;
    int col = lane & 15;                    // i offset (MFMA A row)
    int qd  = lane >> 4;                    // k subgroup (MFMA A k-quad)

    __shared__ float sa2[2][N_];                    // 16 KB (this etype's heads)
    __shared__ float sA[2][TI_][H_ + 1];            // 8.3 KB
    __shared__ float sB[2][TI_][H_ + 1];            // 8.3 KB

    // stage a2 (pre-scaled by log2e) for heads cl=0,1 of etype cp
    for (int q = t; q < 2 * (N_ / 4); q += 512) {
        int cl_ = q >> 9, kk = q & 511;
        ((float4*)sa2[cl_])[kk] =
            ((const float4*)(a2s + (size_t)(cp * 2 + cl_) * BN_ + b * N_))[kk];
    }

    float a1v = a1[(size_t)c * BN_ + b * N_ + i0 + col];          // pre-scaled
    const float* __restrict__ erow = edges + (size_t)(b * N_ + i0 + col) * (N_ * 2);
    const unsigned short* __restrict__ whb0 = WhB + (size_t)(c * B_ + b) * (N_ * 64);

    floatx4 acc[4] = {{0,0,0,0},{0,0,0,0},{0,0,0,0},{0,0,0,0}};
    __syncthreads();                        // sa2 ready

    const int ktBeg = kq * (NKT_ / 4);
    const int ktEnd = ktBeg + NKT_ / 4;     // 16 iterations per wave
    for (int kt = ktBeg; kt < ktEnd; ++kt) {
        const float4* ep = (const float4*)(erow + (size_t)(kt * TK_ + qd * 8) * 2);
        float4 e0 = ep[0], e1 = ep[1], e2 = ep[2], e3 = ep[3];
        bf16x8 bf[4];
        #pragma unroll
        for (int nt = 0; nt < 4; ++nt)
            bf[nt] = *(const bf16x8*)(whb0 + ((size_t)(kt * 4 + qd) * 64 + nt * 16 + col) * 8);
        const float4* sp = (const float4*)&sa2[cl][kt * TK_ + qd * 8];
        float4 s0 = sp[0], s1 = sp[1];
        float az[8] = {s0.x, s0.y, s0.z, s0.w, s1.x, s1.y, s1.z, s1.w};
        float ev[8];
        ev[0] = cp ? e0.y : e0.x; ev[1] = cp ? e0.w : e0.z;
        ev[2] = cp ? e1.y : e1.x; ev[3] = cp ? e1.w : e1.z;
        ev[4] = cp ? e2.y : e2.x; ev[5] = cp ? e2.w : e2.z;
        ev[6] = cp ? e3.y : e3.x; ev[7] = cp ? e3.w : e3.z;
        bf16x8 af;
        #pragma unroll
        for (int j = 0; j < 8; ++j) {
            float sx = a1v + az[j];
            float u  = fmaxf(sx, 0.2f * sx);                 // lrelu (log2 dom.)
            af[j] = (__bf16)fexp2(fmaf(ev[j], L2E_, u));     // P (unnormalized)
        }
        #pragma unroll
        for (int nt = 0; nt < 4; ++nt)
            acc[nt] = __builtin_amdgcn_mfma_f32_16x16x32_bf16(af, bf[nt], acc[nt], 0, 0, 0);
    }

    // ---- combine k-quarters: acc[nt][r] = partial[i0+qd*4+r][nt*16+col]
    if (kq == 2) {
        #pragma unroll
        for (int nt = 0; nt < 4; ++nt)
            #pragma unroll
            for (int r = 0; r < 4; ++r)
                sA[cl][qd * 4 + r][nt * 16 + col] = acc[nt][r];
    } else if (kq == 3) {
        #pragma unroll
        for (int nt = 0; nt < 4; ++nt)
            #pragma unroll
            for (int r = 0; r < 4; ++r)
                sB[cl][qd * 4 + r][nt * 16 + col] = acc[nt][r];
    }
    __syncthreads();
    if (kq == 0) {
        #pragma unroll
        for (int nt = 0; nt < 4; ++nt)
            #pragma unroll
            for (int r = 0; r < 4; ++r)
                acc[nt][r] += sA[cl][qd * 4 + r][nt * 16 + col];
    } else if (kq == 1) {
        #pragma unroll
        for (int nt = 0; nt < 4; ++nt)
            #pragma unroll
            for (int r = 0; r < 4; ++r)
                acc[nt][r] += sB[cl][qd * 4 + r][nt * 16 + col];
    }
    __syncthreads();
    if (kq == 1) {
        #pragma unroll
        for (int nt = 0; nt < 4; ++nt)
            #pragma unroll
            for (int r = 0; r < 4; ++r)
                sA[cl][qd * 4 + r][nt * 16 + col] = acc[nt][r];
    }
    __syncthreads();
    if (kq == 0) {
        if (LAST) {
            #pragma unroll
            for (int nt = 0; nt < 4; ++nt) {
                float bb = bias[cl * H_ + nt * 16 + col];
                #pragma unroll
                for (int r = 0; r < 4; ++r) {
                    float x = acc[nt][r] + sA[cl][qd * 4 + r][nt * 16 + col] + bb;
                    sA[cl][qd * 4 + r][nt * 16 + col] =
                        x > 0.f ? x : (__expf(x) - 1.f);     // elu
                }
            }
        } else {
            unsigned short* out = (unsigned short*)outv;
            #pragma unroll
            for (int nt = 0; nt < 4; ++nt) {
                float bb = bias[cl * H_ + nt * 16 + col];
                #pragma unroll
                for (int r = 0; r < 4; ++r) {
                    float x = acc[nt][r] + sA[cl][qd * 4 + r][nt * 16 + col] + bb;
                    out[((size_t)(b * N_ + i0 + qd * 4 + r)) * D1_ + c * H_ + nt * 16 + col]
                        = f2b(x);
                }
            }
        }
    }
    if (LAST) {
        __syncthreads();
        // block partial: sum of elu over rows and this etype's 2 heads, /4
        if (t < 64) {
            float s = 0.f;
            #pragma unroll
            for (int r = 0; r < TI_; ++r)
                s += sA[0][r][t] + sA[1][r][t];
            ((float*)outv)[((size_t)cp * 512 + g) * 64 + t] = s * 0.25f;
        }
    }
}

// ------------------------------------------------------------- final output
// po[cp*512 + b*128 + it][64] partial row-sums -> out[b][o]
__global__ __launch_bounds__(1024) void out_kernel(
        const float* __restrict__ po, const float* __restrict__ W_out,
        const float* __restrict__ b_out, float* __restrict__ out) {
    int b = blockIdx.x, t = threadIdx.x;
    int d = t & 63, g0 = t >> 6;            // 16 groups
    float s = 0.f;
    #pragma unroll 4
    for (int p = g0; p < 256; p += 16) {
        int cp = p >> 7, it = p & 127;
        s += po[((size_t)cp * 512 + b * 128 + it) * 64 + d];
    }
    __shared__ float red[16][H_];
    red[g0][d] = s;
    __syncthreads();
    if (t < H_) {
        float r = 0.f;
        #pragma unroll
        for (int q = 0; q < 16; ++q) r += red[q][t];
        red[0][t] = r * (1.f / N_);
    }
    __syncthreads();
    if (t < O_) {
        float acc = b_out[t];
        #pragma unroll 8
        for (int dd = 0; dd < H_; ++dd)
            acc += red[0][dd] * W_out[dd * O_ + t];
        out[b * O_ + t] = acc;
    }
}

extern "C" void kernel_launch(void* const* d_in, const int* in_sizes, int n_in,
                              void* d_out, int out_size, void* d_ws, size_t ws_size,
                              hipStream_t stream) {
    const float* nodes = (const float*)d_in[0];
    const float* edges = (const float*)d_in[1];
    const float* W_emb = (const float*)d_in[2];
    const float* b_emb = (const float*)d_in[3];
    const float* Wf0   = (const float*)d_in[4];
    const float* w1_0  = (const float*)d_in[5];
    const float* b1_0  = (const float*)d_in[6];
    const float* w2_0  = (const float*)d_in[7];
    const float* b2_0  = (const float*)d_in[8];
    const float* bias0 = (const float*)d_in[9];
    const float* Wf1   = (const float*)d_in[10];
    const float* w1_1  = (const float*)d_in[11];
    const float* b1_1  = (const float*)d_in[12];
    const float* w2_1  = (const float*)d_in[13];
    const float* b2_1  = (const float*)d_in[14];
    const float* bias1 = (const float*)d_in[15];
    const float* W_out = (const float*)d_in[16];
    const float* b_out = (const float*)d_in[17];

    float* ws = (float*)d_ws;
    unsigned short* state0B = (unsigned short*)ws;                  // 262144 fl
    unsigned short* state1B = (unsigned short*)(ws + 262144);       // 1048576 fl
    unsigned short* WhB  = (unsigned short*)(ws + 262144 + 1048576);// 1048576 fl
    unsigned short* WfB0 = (unsigned short*)(ws + 2359296);         // 8192 fl
    unsigned short* WfB1 = (unsigned short*)(ws + 2367488);         // 32768 fl
    float* a1 = ws + 2400256;                                       // 32768 fl
    float* a2 = ws + 2433024;                                       // 32768 fl
    float* ps = ws + 2465792;                                       // 2097152 fl
    float* po = ws + 4562944;                                       // 65536 fl

    prep_kernel<<<2368, 256, 0, stream>>>(nodes, W_emb, b_emb, Wf0, Wf1,
                                          state0B, WfB0, WfB1);

    // ---- layer 0
    wh_a_mfma_kernel<H_><<<BN_ / TI_, 256, 0, stream>>>(state0B, WfB0, w1_0, b1_0,
                                                        w2_0, b2_0, WhB, a1, a2);
    stats_kernel<<<B_ * NC_ * (N_ / 512), 256, 0, stream>>>(edges, a1, a2, ps);
    scale_kernel<<<1024, 256, 0, stream>>>(ps, WhB);
    mac_kernel<0><<<2 * B_ * (N_ / TI_), 512, 0, stream>>>(edges, a1, a2, WhB, bias0, state1B);
    // ---- layer 1
    wh_a_mfma_kernel<D1_><<<BN_ / TI_, 256, 0, stream>>>(state1B, WfB1, w1_1, b1_1,
                                                         w2_1, b2_1, WhB, a1, a2);
    stats_kernel<<<B_ * NC_ * (N_ / 512), 256, 0, stream>>>(edges, a1, a2, ps);
    scale_kernel<<<1024, 256, 0, stream>>>(ps, WhB);
    mac_kernel<1><<<2 * B_ * (N_ / TI_), 512, 0, stream>>>(edges, a1, a2, WhB, bias1, po);

    out_kernel<<<B_, 1024, 0, stream>>>(po, W_out, b_out, (float*)d_out);
}

// Round 5
// 372.785 us; speedup vs baseline: 1.1862x; 1.1862x over previous
//
#include <hip/hip_runtime.h>
#include <hip/hip_bf16.h>

// GraphNetwork GAT: B=4, N=2048, I=32, H=64, O=32, E=2, HD=2, D1=256
// R11: mac rebuilt around async global_load_lds edge staging (compiler-proof
// prefetch): 512 thr, waves (c, k-half), all 4 c per block (single edge
// pass), triple-buffered 8KB edge tiles, XOR-swizzled LDS (conflict-free
// b128 reads), (512,4) so no VGPR collapse, bijective XCD swizzle for WhB
// L2 locality. stats/wh_a/scale unchanged from R10; out_kernel = R9 form.

constexpr int B_  = 4;
constexpr int N_  = 2048;
constexpr int I_  = 32;
constexpr int H_  = 64;
constexpr int O_  = 32;
constexpr int EH_ = 4;          // E*HD combos, c = e*2 + h
constexpr int D1_ = 256;        // H*HD*E
constexpr int BN_ = B_ * N_;    // 8192
constexpr int NC_ = 64;         // i-chunks for softmax stats
constexpr int CH_ = N_ / NC_;   // 32
constexpr int TI_ = 16;         // msg rows per block (one MFMA m-tile)
constexpr int TK_ = 32;         // k-tile (one MFMA K)
constexpr int NKT_ = N_ / TK_;  // 64 k-tiles
constexpr int NST_ = 32;        // steps per mac block (each kh-wave: 1 kt/step)

typedef __bf16 bf16x8 __attribute__((ext_vector_type(8)));
typedef float floatx4 __attribute__((ext_vector_type(4)));

constexpr float L2E_ = 1.4426950408889634f;   // log2(e)

__device__ __forceinline__ unsigned short f2b(float f) {
    unsigned int u = __float_as_uint(f);
    return (unsigned short)((u + 0x7fffu + ((u >> 16) & 1u)) >> 16);
}

__device__ __forceinline__ float fexp2(float x) {
#if __has_builtin(__builtin_amdgcn_exp2f)
    return __builtin_amdgcn_exp2f(x);      // v_exp_f32 (exp2) direct
#else
    return __expf(x * 0.6931471805599453f);
#endif
}

// async global->LDS 16B per lane; dest = wave-uniform base + lane*16
__device__ __forceinline__ void gl2lds16(const void* g, void* l) {
    __builtin_amdgcn_global_load_lds(
        (const __attribute__((address_space(1))) unsigned int*)g,
        (__attribute__((address_space(3))) unsigned int*)l, 16, 0, 0);
}

// ------------------------------------------------- fused preprocessing
// blocks [0,2048): embed; [2048,2112): pack Wf0 (din=64); [2112,2368): Wf1
__global__ __launch_bounds__(256) void prep_kernel(
        const float* __restrict__ nodes, const float* __restrict__ W_emb,
        const float* __restrict__ b_emb, const float* __restrict__ Wf0,
        const float* __restrict__ Wf1, unsigned short* __restrict__ state0B,
        unsigned short* __restrict__ WfB0, unsigned short* __restrict__ WfB1) {
    int blk = blockIdx.x;
    int t = threadIdx.x;
    __shared__ float sn[4][I_];
    if (blk < 2048) {
        int r = t >> 6, h = t & 63;
        if (t < 4 * I_) {
            int rr = t / I_, ii = t % I_;
            sn[rr][ii] = nodes[(size_t)(blk * 4 + rr) * I_ + ii];
        }
        __syncthreads();
        float acc = b_emb[h];
        #pragma unroll
        for (int i = 0; i < I_; ++i) acc += sn[r][i] * W_emb[i * H_ + h];
        state0B[(size_t)(blk * 4 + r) * H_ + h] = f2b(acc);
    } else if (blk < 2048 + 64) {
        int o = (blk - 2048) * 256 + t;         // din=64
        int k = o & 63, n = (o >> 6) & 63, c = o >> 12;
        WfB0[o] = f2b(Wf0[((size_t)c * 64 + k) * 64 + n]);
    } else {
        int o = (blk - 2112) * 256 + t;         // din=256
        int k = o & 255, n = (o >> 8) & 63, c = o >> 14;
        WfB1[o] = f2b(Wf1[((size_t)c * 256 + k) * 64 + n]);
    }
}

// ---------------------------------------------------- Wh + a1/a2 via MFMA
// a1/a2 outputs are PRE-SCALED by log2(e) for the log2-domain softmax.
template <int DIN>
__global__ __launch_bounds__(256) void wh_a_mfma_kernel(
        const unsigned short* __restrict__ stateB, const unsigned short* __restrict__ WfB,
        const float* __restrict__ w1, const float* __restrict__ b1,
        const float* __restrict__ w2, const float* __restrict__ b2,
        unsigned short* __restrict__ WhB, float* __restrict__ a1,
        float* __restrict__ a2) {
    int t = threadIdx.x;
    int lane = t & 63, wv = t >> 6;             // wv = c
    int col = lane & 15, qd = lane >> 4;
    int bn0 = blockIdx.x * TI_;                 // grid BN/16 = 512
    int b = bn0 >> 11;

    floatx4 acc[4] = {{0,0,0,0},{0,0,0,0},{0,0,0,0},{0,0,0,0}};
    const unsigned short* __restrict__ ap = stateB + (size_t)(bn0 + col) * DIN + qd * 8;
    const unsigned short* __restrict__ bp = WfB + ((size_t)(wv * 64 + col) * DIN + qd * 8);
    #pragma unroll
    for (int k0 = 0; k0 < DIN; k0 += 32) {
        bf16x8 af = *(const bf16x8*)(ap + k0);
        #pragma unroll
        for (int nt = 0; nt < 4; ++nt) {
            bf16x8 bf = *(const bf16x8*)(bp + (size_t)nt * 16 * DIN + k0);
            acc[nt] = __builtin_amdgcn_mfma_f32_16x16x32_bf16(af, bf, acc[nt], 0, 0, 0);
        }
    }
    // acc[nt][r] = Wh[bn0 + qd*4 + r][nt*16 + col]
    int nb = ((bn0 & 2047) >> 3) + (qd >> 1);
    #pragma unroll
    for (int nt = 0; nt < 4; ++nt) {
        unsigned int lo = (unsigned int)f2b(acc[nt][0]) | ((unsigned int)f2b(acc[nt][1]) << 16);
        unsigned int hi = (unsigned int)f2b(acc[nt][2]) | ((unsigned int)f2b(acc[nt][3]) << 16);
        uint2 v = make_uint2(lo, hi);
        *(uint2*)(WhB + ((((size_t)(wv * B_ + b) * 256 + nb) * 64 + nt * 16 + col) * 8
                         + (qd & 1) * 4)) = v;
    }
    // a1/a2 row dots, butterfly over col lanes
    float p1[4] = {}, p2[4] = {};
    #pragma unroll
    for (int nt = 0; nt < 4; ++nt) {
        float w1n = w1[wv * H_ + nt * 16 + col];
        float w2n = w2[wv * H_ + nt * 16 + col];
        #pragma unroll
        for (int r = 0; r < 4; ++r) {
            p1[r] += acc[nt][r] * w1n;
            p2[r] += acc[nt][r] * w2n;
        }
    }
    #pragma unroll
    for (int m = 1; m < 16; m <<= 1)
        #pragma unroll
        for (int r = 0; r < 4; ++r) {
            p1[r] += __shfl_xor(p1[r], m, 64);
            p2[r] += __shfl_xor(p2[r], m, 64);
        }
    if (col == 0) {
        float b1c = b1[wv], b2c = b2[wv];
        #pragma unroll
        for (int r = 0; r < 4; ++r) {
            a1[(size_t)wv * BN_ + bn0 + qd * 4 + r] = (p1[r] + b1c) * L2E_;
            a2[(size_t)wv * BN_ + bn0 + qd * 4 + r] = (p2[r] + b2c) * L2E_;
        }
    }
}

// -------------------------------------------------- column softmax stats
// Direct sum-of-exp2 (range-safe). 2 j per thread, float4 edge loads,
// 8 independent accumulation chains. Grid B*NC*(N/512) = 1024.
__global__ __launch_bounds__(256) void stats_kernel(
        const float* __restrict__ edges, const float* __restrict__ a1,
        const float* __restrict__ a2, float* __restrict__ ps) {
    int blk = blockIdx.x;
    int jt = blk & 3;                           // 4 j-tiles of 512
    int ic = (blk >> 2) & (NC_ - 1);
    int b  = blk >> 8;
    int t = threadIdx.x;
    int j0 = jt * 512 + t * 2;
    __shared__ float sa1[EH_][CH_];
    if (t < EH_ * CH_) {
        int cc = t >> 5, ii = t & 31;
        sa1[cc][ii] = a1[(size_t)cc * BN_ + b * N_ + ic * CH_ + ii];
    }
    __syncthreads();
    float a2x[EH_], a2y[EH_], s0[EH_], s1[EH_];
    #pragma unroll
    for (int cc = 0; cc < EH_; ++cc) {
        float2 av = *(const float2*)(a2 + (size_t)cc * BN_ + b * N_ + j0);
        a2x[cc] = av.x; a2y[cc] = av.y;
        s0[cc] = 0.f; s1[cc] = 0.f;
    }
    const float4* __restrict__ ep =
        (const float4*)edges + (((size_t)(b * N_ + ic * CH_) * N_ + j0) >> 1);
    #pragma unroll 4
    for (int ii = 0; ii < CH_; ++ii) {
        float4 u = ep[(size_t)ii * (N_ >> 1)];  // [e0 j0, e1 j0, e0 j1, e1 j1]
        #pragma unroll
        for (int cc = 0; cc < EH_; ++cc) {
            float base = sa1[cc][ii];
            float xa = base + a2x[cc];
            float xb = base + a2y[cc];
            float la = fmaxf(xa, 0.2f * xa);
            float lb = fmaxf(xb, 0.2f * xb);
            float ea = (cc < 2) ? u.x : u.y;
            float eb = (cc < 2) ? u.z : u.w;
            s0[cc] += fexp2(fmaf(ea, L2E_, la));
            s1[cc] += fexp2(fmaf(eb, L2E_, lb));
        }
    }
    #pragma unroll
    for (int cc = 0; cc < EH_; ++cc)
        *(float2*)&ps[((size_t)ic * EH_ + cc) * BN_ + b * N_ + j0] =
            make_float2(s0[cc], s1[cc]);
}

// ---------------------------------- fused combine + WhB denominator fold
__global__ __launch_bounds__(256) void scale_kernel(
        const float* __restrict__ ps, unsigned short* __restrict__ WhB) {
    int t = threadIdx.x;
    int m0 = blockIdx.x * 256;              // chunk base, grid 1024
    int cb = m0 >> 14;
    int c = cb >> 2, b = cb & 3;
    int k0 = ((m0 >> 6) & 255) * 8;         // 32 consecutive k
    __shared__ float sD[32];
    if (t < 32) {
        float S = 0.f;
        const float* pp = ps + (size_t)c * BN_ + b * N_ + k0 + t;
        #pragma unroll 8
        for (int ic = 0; ic < NC_; ++ic) S += pp[(size_t)ic * EH_ * BN_];
        sD[t] = 1.f / S;
    }
    __syncthreads();
    unsigned short* wp = WhB + (size_t)(m0 + t) * 8;
    uint4 w = *(const uint4*)wp;
    int nbo = (t >> 6) * 8;
    unsigned int words[4] = {w.x, w.y, w.z, w.w};
    #pragma unroll
    for (int q = 0; q < 4; ++q) {
        float lo = __uint_as_float((words[q] & 0xffffu) << 16) * sD[nbo + 2 * q];
        float hi = __uint_as_float(words[q] & 0xffff0000u) * sD[nbo + 2 * q + 1];
        words[q] = (unsigned)f2b(lo) | ((unsigned)f2b(hi) << 16);
    }
    *(uint4*)wp = make_uint4(words[0], words[1], words[2], words[3]);
}

// ------------------------------------------------------------- MFMA MAC
// 8 waves = (c = wv&3, kh = wv>>2). Per step s: all 8 waves DMA-stage 1KB of
// the step-(s+1) edge tile (async global_load_lds, triple-buffered; XOR-
// swizzled source so LDS reads are conflict-free), barrier, then each wave
// computes one MFMA k-tile (kt = kh*32 + s). a2 in LDS; denominator folded
// into WhB. LAST=0: state1B bf16; LAST=1: po[blk][64] partials.
template <int LAST>
__global__ __launch_bounds__(512, 4) void mac_kernel(
        const float* __restrict__ edges, const float* __restrict__ a1,
        const float* __restrict__ a2s, const unsigned short* __restrict__ WhB,
        const float* __restrict__ bias, void* __restrict__ outv) {
    int t = threadIdx.x;                    // 512
    int blk0 = blockIdx.x;                  // hw index, grid 512
    int blk = ((blk0 & 7) << 6) + (blk0 >> 3);   // bijective XCD swizzle
    int b = blk >> 7;
    int i0 = (blk & 127) * TI_;
    int lane = t & 63, wv = t >> 6;
    int c  = wv & 3;                        // edgetype*2 + head
    int kh = wv >> 2;                       // k-half
    int col = lane & 15;                    // i offset (MFMA A row)
    int qd  = lane >> 4;                    // k subgroup (MFMA A k-quad)
    int esel = c >> 1;                      // edge component

    __shared__ float sa2[EH_][N_];                              // 32 KB
    __shared__ __attribute__((aligned(16))) unsigned char eds[3][2][TI_][256]; // 24 KB
    __shared__ float sred[EH_][TI_][H_ + 1];                    // 16.6 KB

    // stage a2 (pre-scaled by log2e): 4 x N floats, coalesced float4
    for (int q = t; q < EH_ * (N_ / 4); q += 512) {
        int cc = q >> 9, kk = q & 511;
        ((float4*)sa2[cc])[kk] =
            ((const float4*)(a2s + (size_t)cc * BN_ + b * N_))[kk];
    }

    float a1v = a1[(size_t)c * BN_ + b * N_ + i0 + col];          // pre-scaled
    const unsigned short* __restrict__ whb0 = WhB + (size_t)(c * B_ + b) * (N_ * 64);

    // staging role of this thread: wave wv stages chunk wv (1KB) of each tile
    // tile T=wv>>2 (kh half), rows 4*(wv&3) + lane/16, swizzled slot
    int srow  = 4 * (wv & 3) + (lane >> 4);
    int sslot = (lane & 15) ^ (srow & 15);        // pre-swizzled global slot
    const char* gsrc = (const char*)edges
        + ((size_t)(b * N_ + i0 + srow) * N_ + (size_t)(wv >> 2) * 1024) * 8
        + sslot * 16;
    char* ldst = (char*)&eds[0][0][0][0] + wv * 1024;   // + buf*8192 per step

    floatx4 acc[4] = {{0,0,0,0},{0,0,0,0},{0,0,0,0},{0,0,0,0}};

    gl2lds16(gsrc, ldst);                   // stage step 0 -> buf 0
    for (int s = 0; s < NST_; ++s) {
        if (s + 1 < NST_)
            gl2lds16(gsrc + (size_t)(s + 1) * 256,
                     ldst + (size_t)(((s + 1) % 3)) * 8192);
        __syncthreads();                    // publishes stage(s); sa2 on s=0

        int kt = kh * NST_ + s;
        // edge fragment from swizzled LDS tile (conflict-free b128)
        const char* ebase = (const char*)&eds[0][0][0][0]
                          + (s % 3) * 8192 + kh * 4096 + col * 256;
        float ev[8];
        #pragma unroll
        for (int jj = 0; jj < 4; ++jj) {
            int sg = qd * 4 + jj;
            float4 v = *(const float4*)(ebase + ((sg ^ (col & 15)) * 16));
            ev[2 * jj]     = esel ? v.y : v.x;
            ev[2 * jj + 1] = esel ? v.w : v.z;
        }
        const float4* sp = (const float4*)&sa2[c][kt * TK_ + qd * 8];
        float4 z0 = sp[0], z1 = sp[1];
        float az[8] = {z0.x, z0.y, z0.z, z0.w, z1.x, z1.y, z1.z, z1.w};
        bf16x8 bf[4];
        #pragma unroll
        for (int nt = 0; nt < 4; ++nt)
            bf[nt] = *(const bf16x8*)(whb0 + ((size_t)(kt * 4 + qd) * 64 + nt * 16 + col) * 8);
        bf16x8 af;
        #pragma unroll
        for (int j = 0; j < 8; ++j) {
            float sx = a1v + az[j];
            float u  = fmaxf(sx, 0.2f * sx);                 // lrelu (log2 dom.)
            af[j] = (__bf16)fexp2(fmaf(ev[j], L2E_, u));     // P (unnormalized)
        }
        #pragma unroll
        for (int nt = 0; nt < 4; ++nt)
            acc[nt] = __builtin_amdgcn_mfma_f32_16x16x32_bf16(af, bf[nt], acc[nt], 0, 0, 0);
    }

    // ---- epilogue: acc[nt][r] = msg_partial[i0+qd*4+r][nt*16+col]
    if (kh == 1) {
        #pragma unroll
        for (int nt = 0; nt < 4; ++nt)
            #pragma unroll
            for (int r = 0; r < 4; ++r)
                sred[c][qd * 4 + r][nt * 16 + col] = acc[nt][r];
    }
    __syncthreads();
    if (kh == 0) {
        if (LAST) {
            #pragma unroll
            for (int nt = 0; nt < 4; ++nt) {
                float bb = bias[(c & 1) * H_ + nt * 16 + col];
                #pragma unroll
                for (int r = 0; r < 4; ++r) {
                    float x = acc[nt][r] + sred[c][qd * 4 + r][nt * 16 + col] + bb;
                    sred[c][qd * 4 + r][nt * 16 + col] =
                        x > 0.f ? x : (__expf(x) - 1.f);     // elu
                }
            }
        } else {
            unsigned short* out = (unsigned short*)outv;
            #pragma unroll
            for (int nt = 0; nt < 4; ++nt) {
                float bb = bias[(c & 1) * H_ + nt * 16 + col];
                #pragma unroll
                for (int r = 0; r < 4; ++r) {
                    float x = acc[nt][r] + sred[c][qd * 4 + r][nt * 16 + col] + bb;
                    out[((size_t)(b * N_ + i0 + qd * 4 + r)) * D1_ + c * H_ + nt * 16 + col]
                        = f2b(x);
                }
            }
        }
    }
    if (LAST) {
        __syncthreads();
        // block partial: mean over c, sum over the 16 rows -> po[blk][64]
        if (t < 64) {
            float s = 0.f;
            #pragma unroll
            for (int r = 0; r < TI_; ++r)
                s += sred[0][r][t] + sred[1][r][t] + sred[2][r][t] + sred[3][r][t];
            ((float*)outv)[(size_t)blk * 64 + t] = s * 0.25f;
        }
    }
}

// ------------------------------------------------------------- final output
// po[b*128+g][64] partial row-sums -> out[b][o]
__global__ __launch_bounds__(256) void out_kernel(
        const float* __restrict__ po, const float* __restrict__ W_out,
        const float* __restrict__ b_out, float* __restrict__ out) {
    int b = blockIdx.x, t = threadIdx.x;
    int d = t & 63, g0 = t >> 6;
    float s = 0.f;
    for (int g = g0; g < 128; g += 4) s += po[(size_t)(b * 128 + g) * 64 + d];
    __shared__ float red[4][H_];
    red[g0][d] = s;
    __syncthreads();
    if (t < H_) red[0][t] = (red[0][t] + red[1][t] + red[2][t] + red[3][t]) * (1.f / N_);
    __syncthreads();
    if (t < O_) {
        float acc = b_out[t];
        #pragma unroll 8
        for (int dd = 0; dd < H_; ++dd)
            acc += red[0][dd] * W_out[dd * O_ + t];
        out[b * O_ + t] = acc;
    }
}

extern "C" void kernel_launch(void* const* d_in, const int* in_sizes, int n_in,
                              void* d_out, int out_size, void* d_ws, size_t ws_size,
                              hipStream_t stream) {
    const float* nodes = (const float*)d_in[0];
    const float* edges = (const float*)d_in[1];
    const float* W_emb = (const float*)d_in[2];
    const float* b_emb = (const float*)d_in[3];
    const float* Wf0   = (const float*)d_in[4];
    const float* w1_0  = (const float*)d_in[5];
    const float* b1_0  = (const float*)d_in[6];
    const float* w2_0  = (const float*)d_in[7];
    const float* b2_0  = (const float*)d_in[8];
    const float* bias0 = (const float*)d_in[9];
    const float* Wf1   = (const float*)d_in[10];
    const float* w1_1  = (const float*)d_in[11];
    const float* b1_1  = (const float*)d_in[12];
    const float* w2_1  = (const float*)d_in[13];
    const float* b2_1  = (const float*)d_in[14];
    const float* bias1 = (const float*)d_in[15];
    const float* W_out = (const float*)d_in[16];
    const float* b_out = (const float*)d_in[17];

    float* ws = (float*)d_ws;
    unsigned short* state0B = (unsigned short*)ws;                  // 262144 fl
    unsigned short* state1B = (unsigned short*)(ws + 262144);       // 1048576 fl
    unsigned short* WhB  = (unsigned short*)(ws + 262144 + 1048576);// 1048576 fl
    unsigned short* WfB0 = (unsigned short*)(ws + 2359296);         // 8192 fl
    unsigned short* WfB1 = (unsigned short*)(ws + 2367488);         // 32768 fl
    float* a1 = ws + 2400256;                                       // 32768 fl
    float* a2 = ws + 2433024;                                       // 32768 fl
    float* ps = ws + 2465792;                                       // 2097152 fl
    float* po = ws + 4562944;                                       // 32768 fl

    prep_kernel<<<2368, 256, 0, stream>>>(nodes, W_emb, b_emb, Wf0, Wf1,
                                          state0B, WfB0, WfB1);

    // ---- layer 0
    wh_a_mfma_kernel<H_><<<BN_ / TI_, 256, 0, stream>>>(state0B, WfB0, w1_0, b1_0,
                                                        w2_0, b2_0, WhB, a1, a2);
    stats_kernel<<<B_ * NC_ * (N_ / 512), 256, 0, stream>>>(edges, a1, a2, ps);
    scale_kernel<<<1024, 256, 0, stream>>>(ps, WhB);
    mac_kernel<0><<<B_ * (N_ / TI_), 512, 0, stream>>>(edges, a1, a2, WhB, bias0, state1B);
    // ---- layer 1
    wh_a_mfma_kernel<D1_><<<BN_ / TI_, 256, 0, stream>>>(state1B, WfB1, w1_1, b1_1,
                                                         w2_1, b2_1, WhB, a1, a2);
    stats_kernel<<<B_ * NC_ * (N_ / 512), 256, 0, stream>>>(edges, a1, a2, ps);
    scale_kernel<<<1024, 256, 0, stream>>>(ps, WhB);
    mac_kernel<1><<<B_ * (N_ / TI_), 512, 0, stream>>>(edges, a1, a2, WhB, bias1, po);

    out_kernel<<<B_, 256, 0, stream>>>(po, W_out, b_out, (float*)d_out);
}